// Round 7
// baseline (244.207 us; speedup 1.0000x reference)
//
#include <hip/hip_runtime.h>

#define HH 128
#define WW 128
#define CC 96
#define KK 7

// Dual-column-tile streaming morphological dilation (7x7 max-plus, zero-pad,
// ReLU folded). Model after 6 rounds: true VALU issue ~26us (VALUBusy is 2x
// overstated by the gfx94x SIMD-16 formula on SIMD-32 gfx950), ~45us exposed
// load latency; residency pinned ~3 waves/SIMD in every variant, per-strip
// compute (704 cyc) < latency (900 cyc) -> coverage-limited equilibrium at
// 2.4 TB/s. Fix: each thread processes TWO column tiles (tc0, tc0+64) of the
// same plane over the same 14 row strips: per-strip compute doubles to
// ~1408 cyc (> latency, covered at distance 1), 6 independent loads per
// strip, same VMEM:output ratio (no halo inflation - R3's poison), weights
// still SGPR-shared. Block = one full (b,c) plane; grid 1536.
//
// Thread t: cg = t&15 -> cols [4cg, 4cg+4) and [4cg+64, 4cg+68); rg = t>>4
// -> out rows [8rg, 8rg+8). Rolling 2-strip buffer, static s&1 indexing.
// Horizontal edge handling via pointer redirect at issue + zero-select at
// consume (only cg==0 left of tile1, cg==15 right of tile2 need it).

__global__ __launch_bounds__(256, 3) void morph_kernel(
    const float* __restrict__ x, const float* __restrict__ weight,
    float* __restrict__ out) {
  const int t = threadIdx.x;
  const int cg = t & 15;   // col group 0..15
  const int rg = t >> 4;   // row group 0..15
  const int plane = blockIdx.x;  // b*CC + c
  const int c = plane % CC;

  const float* __restrict__ xp = x + (size_t)plane * (HH * WW);
  float* __restrict__ op = out + (size_t)plane * (HH * WW);
  const float* __restrict__ Wc = weight + c * (KK * KK);

  // Preload 49 channel weights; force into SGPRs (block-uniform).
  float wv[KK * KK];
#pragma unroll
  for (int k = 0; k < KK * KK; ++k)
    wv[k] = __int_as_float(__builtin_amdgcn_readfirstlane(__float_as_int(Wc[k])));

  const int tc0 = cg << 2;    // tile1 first col (0..60); tile2 = tc0+64
  const int row0 = rg << 3;   // first out row (0..120)
  const bool lok = (tc0 >= 4);             // false only for cg==0
  const bool rok2 = (tc0 + 64 <= WW - 8);  // false only for cg==15

  // Base pointers for the 6 loads per strip; strip s adds s*WW (imm offset).
  // Edge redirect: out-of-plane 16B windows point at an always-valid strip;
  // values zero-selected at consume.
  const float* pb = xp + (row0 - 3) * WW + (tc0 - 4);
  const float* q0 = lok ? pb : pb + 4;    // tile1 A  (cols tc0-4..tc0-1)
  const float* q1 = pb + 4;               // tile1 B  (cols tc0..tc0+3)
  const float* q2 = pb + 8;               // tile1 C  (cols tc0+4..tc0+7)
  const float* q3 = pb + 64;              // tile2 A
  const float* q4 = pb + 68;              // tile2 B
  const float* q5 = rok2 ? pb + 72 : pb + 68;  // tile2 C

  // Rolling 2-deep strip buffers (distance-1 prefetch), static indexing.
  float4 S1[2][3], S2[2][3];

#define LOAD_STRIP(slot, s)                                                  \
  do {                                                                       \
    const int r_ = row0 - 3 + (s);                                           \
    if ((unsigned)r_ < (unsigned)HH) {                                       \
      S1[slot][0] = *(const float4*)(q0 + (s) * WW);                         \
      S1[slot][1] = *(const float4*)(q1 + (s) * WW);                         \
      S1[slot][2] = *(const float4*)(q2 + (s) * WW);                         \
      S2[slot][0] = *(const float4*)(q3 + (s) * WW);                         \
      S2[slot][1] = *(const float4*)(q4 + (s) * WW);                         \
      S2[slot][2] = *(const float4*)(q5 + (s) * WW);                         \
    } else {                                                                 \
      const float4 z_ = make_float4(0.f, 0.f, 0.f, 0.f);                     \
      S1[slot][0] = z_; S1[slot][1] = z_; S1[slot][2] = z_;                  \
      S2[slot][0] = z_; S2[slot][1] = z_; S2[slot][2] = z_;                  \
    }                                                                        \
  } while (0)

  // Accumulators: ReLU folded (start at 0). 2 tiles x 8 rows x 4 cols.
  float acc1[8][4], acc2[8][4];
#pragma unroll
  for (int y = 0; y < 8; ++y)
#pragma unroll
    for (int q = 0; q < 4; ++q) { acc1[y][q] = 0.f; acc2[y][q] = 0.f; }

  LOAD_STRIP(0, 0);  // prologue

#pragma unroll
  for (int s = 0; s < 14; ++s) {
    if (s + 1 < 14) LOAD_STRIP((s + 1) & 1, s + 1);

    const int sl = s & 1;
    // Assemble 10-wide strips (cols tcX-3..tcX+6); zero-select edges here.
    const float4 A1 = S1[sl][0], B1 = S1[sl][1], C1 = S1[sl][2];
    const float4 A2 = S2[sl][0], B2 = S2[sl][1], C2 = S2[sl][2];
    const float e1[10] = {lok ? A1.y : 0.f, lok ? A1.z : 0.f, lok ? A1.w : 0.f,
                          B1.x, B1.y, B1.z, B1.w, C1.x, C1.y, C1.z};
    const float e2[10] = {A2.y, A2.z, A2.w, B2.x, B2.y, B2.z, B2.w,
                          rok2 ? C2.x : 0.f, rok2 ? C2.y : 0.f,
                          rok2 ? C2.z : 0.f};

#pragma unroll
    for (int yl = 0; yl < 8; ++yl) {
      const int i = s - yl;            // weight row; folds at compile time
      if (i < 0 || i >= KK) continue;  // static guard (full unroll)
      const float w0 = wv[i * 7 + 0], w1 = wv[i * 7 + 1], w2 = wv[i * 7 + 2],
                  w3 = wv[i * 7 + 3], w4 = wv[i * 7 + 4], w5 = wv[i * 7 + 5],
                  w6 = wv[i * 7 + 6];
#pragma unroll
      for (int q = 0; q < 4; ++q) {
        {
          const float t0 = e1[q + 0] + w0;
          const float t1 = e1[q + 1] + w1;
          const float t2 = e1[q + 2] + w2;
          const float t3 = e1[q + 3] + w3;
          const float t4 = e1[q + 4] + w4;
          const float t5 = e1[q + 5] + w5;
          const float t6 = e1[q + 6] + w6;
          float m = acc1[yl][q];
          m = fmaxf(fmaxf(m, t0), t1);  // fuses to v_max3_f32 (verified R4)
          m = fmaxf(fmaxf(m, t2), t3);
          m = fmaxf(fmaxf(m, t4), t5);
          acc1[yl][q] = fmaxf(m, t6);
        }
        {
          const float t0 = e2[q + 0] + w0;
          const float t1 = e2[q + 1] + w1;
          const float t2 = e2[q + 2] + w2;
          const float t3 = e2[q + 3] + w3;
          const float t4 = e2[q + 4] + w4;
          const float t5 = e2[q + 5] + w5;
          const float t6 = e2[q + 6] + w6;
          float m = acc2[yl][q];
          m = fmaxf(fmaxf(m, t0), t1);
          m = fmaxf(fmaxf(m, t2), t3);
          m = fmaxf(fmaxf(m, t4), t5);
          acc2[yl][q] = fmaxf(m, t6);
        }
      }
    }

    // Output row (row0 + s - 6) complete for both tiles.
    if (s >= 6) {
      const int yl = s - 6;
      float* orow = op + (size_t)(row0 + yl) * WW + tc0;
      *(float4*)(orow) =
          make_float4(acc1[yl][0], acc1[yl][1], acc1[yl][2], acc1[yl][3]);
      *(float4*)(orow + 64) =
          make_float4(acc2[yl][0], acc2[yl][1], acc2[yl][2], acc2[yl][3]);
    }
  }
#undef LOAD_STRIP
}

extern "C" void kernel_launch(void* const* d_in, const int* in_sizes, int n_in,
                              void* d_out, int out_size, void* d_ws, size_t ws_size,
                              hipStream_t stream) {
  const float* x = (const float*)d_in[0];
  const float* w = (const float*)d_in[1];
  float* out = (float*)d_out;
  // 16 batches * 96 channels; one block per full plane
  const int nblocks = 16 * CC;
  morph_kernel<<<nblocks, 256, 0, stream>>>(x, w, out);
}

// Round 8
// 184.624 us; speedup vs baseline: 1.3227x; 1.3227x over previous
//
#include <hip/hip_runtime.h>

#define HH 128
#define WW 128
#define CC 96
#define KK 7

#define LROWS 70   // 64 out rows + 6 halo rows
#define LF (LROWS * WW)          // 8960 floats = 35840 B LDS
#define NSLOT ((67 * WW) / 4)    // 2144 float4 slots staged (67 valid rows)

// LDS-pipelined morphological dilation (7x7 max-plus, zero-pad, ReLU folded).
// Diagnosis after 7 rounds: VALU issue floor ~26us (true, SIMD-32), memory
// floor ~26us, measured 71us -> ~45us exposed HBM latency because loads are
// issued sparsely (3:1 compute:load interleave -> only ~3.5KB/CU outstanding
// vs ~9KB BDP) and residency is pinned ~3 waves/SIMD. Fix: decouple. Each
// block async-copies its 67 valid rows LINEARLY into LDS via
// global_load_lds_dwordx4 (dense issue: 9 back-to-back 1KB wave-instrs, no
// VGPR round trip, HBM saturates), zero-fills the 3 out-of-plane halo rows,
// one barrier, then runs the proven R6 core from LDS (latency 120cyc <<
// 352cyc/strip compute). 4 blocks/CU resident stagger stage/compute phases.

typedef __attribute__((address_space(1))) const void gv_t;
typedef __attribute__((address_space(3))) void lv_t;

__device__ __forceinline__ void gload_lds16(const float* g, float* l) {
  // LDS dest is wave-uniform base + lane*16 (m104); our per-lane l is exactly
  // firstlane(l) + lane*16 by construction (linear copy), so this is safe.
  __builtin_amdgcn_global_load_lds((gv_t*)g, (lv_t*)(unsigned)(uintptr_t)l,
                                   16, 0, 0);
}

__global__ __launch_bounds__(256, 4) void morph_kernel(
    const float* __restrict__ x, const float* __restrict__ weight,
    float* __restrict__ out) {
  __shared__ float lds[LF];

  const int t = threadIdx.x;
  const int half = blockIdx.x & 1;
  const int plane = blockIdx.x >> 1;  // b*CC + c
  const int c = plane % CC;

  const float* __restrict__ xp = x + (size_t)plane * (HH * WW);
  float* __restrict__ op = out + (size_t)plane * (HH * WW);
  const float* __restrict__ Wc = weight + c * (KK * KK);

  // Preload 49 channel weights; force into SGPRs (block-uniform). Issued
  // before staging so the loads overlap it.
  float wv[KK * KK];
#pragma unroll
  for (int k = 0; k < KK * KK; ++k)
    wv[k] = __int_as_float(__builtin_amdgcn_readfirstlane(__float_as_int(Wc[k])));

  // ---- Stage tile into LDS. ----
  // half==0: lds rows 0..2 = global rows -3..-1 (zeros), lds 3..69 <- g 0..66
  // half==1: lds rows 0..66 <- g 61..127, lds rows 67..69 = g 128..130 (zeros)
  const int rv0 = half ? 0 : 3;     // first valid lds row
  const int zrow0 = half ? 67 : 0;  // first zero lds row
  const int grow0 = half ? 61 : 0;  // global row of first valid lds row

  if (t < 96) {  // 3 rows * 128 floats = 96 float4 of zeros
    *(float4*)&lds[zrow0 * WW + t * 4] = make_float4(0.f, 0.f, 0.f, 0.f);
  }

  {
    // Purely linear 34304-byte copy: both layouts are row-major 512B rows.
    const float* gsrc = xp + grow0 * WW;
    float* ldst = &lds[rv0 * WW];
#pragma unroll
    for (int k = 0; k < 9; ++k) {
      const int slot = k * 256 + t;
      if (slot < NSLOT) gload_lds16(gsrc + slot * 4, ldst + slot * 4);
    }
  }
  __syncthreads();  // drains vmcnt (global_load_lds) + lgkmcnt (zero writes)

  // ---- Compute from LDS (R6 core unchanged). ----
  const int cg = t & 31;
  const int rg = t >> 5;
  const int tc0 = cg << 2;     // first out col
  const int r0l = rg << 3;     // first out row, LOCAL (= lds strip row base)
  const bool lok = (tc0 >= 4);
  const bool rok = (tc0 <= WW - 8);

  // Strip s lives at lds row r0l + s (lds row 0 = out-row0 - 3 both halves).
  const float* lp = &lds[r0l * WW + tc0];
  const float* qA = lok ? lp - 4 : lp;  // cols tc0-4..tc0-1 (redirected cg==0)
  const float* qB = lp;                 // cols tc0..tc0+3
  const float* qC = rok ? lp + 4 : lp;  // cols tc0+4..tc0+7 (redirected cg==31)

  float acc[8][4];
#pragma unroll
  for (int y = 0; y < 8; ++y)
#pragma unroll
    for (int q = 0; q < 4; ++q) acc[y][q] = 0.f;  // ReLU folded: start at 0

  // Rolling 2-deep strip buffer (distance-1 prefetch), static indexing.
  float4 S[2][3];
#define LOAD_STRIP(slot, s)                      \
  do {                                           \
    S[slot][0] = *(const float4*)(qA + (s) * WW); \
    S[slot][1] = *(const float4*)(qB + (s) * WW); \
    S[slot][2] = *(const float4*)(qC + (s) * WW); \
  } while (0)

  LOAD_STRIP(0, 0);

#pragma unroll
  for (int s = 0; s < 14; ++s) {
    if (s + 1 < 14) LOAD_STRIP((s + 1) & 1, s + 1);

    const int sl = s & 1;
    const float4 A = S[sl][0], B = S[sl][1], C = S[sl][2];
    // 10-wide window, cols tc0-3..tc0+6; zero-select plane edges.
    const float e[10] = {lok ? A.y : 0.f, lok ? A.z : 0.f, lok ? A.w : 0.f,
                         B.x, B.y, B.z, B.w,
                         rok ? C.x : 0.f, rok ? C.y : 0.f, rok ? C.z : 0.f};

#pragma unroll
    for (int yl = 0; yl < 8; ++yl) {
      const int i = s - yl;            // weight row; folds at compile time
      if (i < 0 || i >= KK) continue;  // static guard (full unroll)
      const float w0 = wv[i * 7 + 0], w1 = wv[i * 7 + 1], w2 = wv[i * 7 + 2],
                  w3 = wv[i * 7 + 3], w4 = wv[i * 7 + 4], w5 = wv[i * 7 + 5],
                  w6 = wv[i * 7 + 6];
#pragma unroll
      for (int q = 0; q < 4; ++q) {
        const float t0 = e[q + 0] + w0;
        const float t1 = e[q + 1] + w1;
        const float t2 = e[q + 2] + w2;
        const float t3 = e[q + 3] + w3;
        const float t4 = e[q + 4] + w4;
        const float t5 = e[q + 5] + w5;
        const float t6 = e[q + 6] + w6;
        float m = acc[yl][q];
        m = fmaxf(fmaxf(m, t0), t1);  // fuses to v_max3_f32 (verified R4)
        m = fmaxf(fmaxf(m, t2), t3);
        m = fmaxf(fmaxf(m, t4), t5);
        acc[yl][q] = fmaxf(m, t6);
      }
    }

    // Output row (local r0l + s - 6) complete.
    if (s >= 6) {
      const int yl = s - 6;
      float4 o = make_float4(acc[yl][0], acc[yl][1], acc[yl][2], acc[yl][3]);
      *(float4*)(op + (size_t)(half * 64 + r0l + yl) * WW + tc0) = o;
    }
  }
#undef LOAD_STRIP
}

extern "C" void kernel_launch(void* const* d_in, const int* in_sizes, int n_in,
                              void* d_out, int out_size, void* d_ws, size_t ws_size,
                              hipStream_t stream) {
  const float* x = (const float*)d_in[0];
  const float* w = (const float*)d_in[1];
  float* out = (float*)d_out;
  // 16 batches * 96 channels * 2 half-planes
  const int nblocks = 16 * CC * 2;
  morph_kernel<<<nblocks, 256, 0, stream>>>(x, w, out);
}